// Round 7
// baseline (315.070 us; speedup 1.0000x reference)
//
#include <hip/hip_runtime.h>
#include <stdint.h>

// ---------------------------------------------------------------------------
// GCN 2-layer. R17: XCD-sliced gathers (R16, FETCH 86->39MB confirmed) with the
// VALU stripped back out: wave = 1 node x 4 edge-groups (group g = edges
// 2g,2g+1 per 8-batch) -> per-node exact len8 (no cross-node max waste);
// col pre-padded with id=N in k0 -> ids loaded directly (no bpermute, no
// per-lane pad selects); zero-row pads. Cross-group shfl tree-reduce epilogue.
// 5 dispatches: k0(zero cursor+pads+g_out | prep_w | col=N fill) ->
// k5(gemm1(+)fill) -> aggp<false> -> gemm2k(dinv-fold) -> aggp<true>.
// ---------------------------------------------------------------------------

#define CAP 96

typedef __attribute__((ext_vector_type(8))) short short8;
typedef __attribute__((ext_vector_type(4))) float f32x4;

__device__ __forceinline__ uint16_t bf16rne(float f) {
    uint32_t u = __float_as_uint(f);
    uint32_t r = (u + 0x7fffu + ((u >> 16) & 1u)) >> 16;
    return (uint16_t)r;
}
__device__ __forceinline__ float bf_lo(uint32_t v) { return __uint_as_float(v << 16); }
__device__ __forceinline__ float bf_hi(uint32_t v) { return __uint_as_float(v & 0xffff0000u); }

// ---- K0 (512 thr): zero cursor(N+1)+slice pad rows | prep_w | zero g_out |
//      fill col with pad id = N ----
__global__ __launch_bounds__(512) void k0(int* __restrict__ cursor, int nbC, int N,
                                          const float* __restrict__ W1,
                                          const float* __restrict__ W2,
                                          uint16_t* __restrict__ Wf1,
                                          uint16_t* __restrict__ Wf2,
                                          float* __restrict__ g_out, int nbZ,
                                          uint32_t* __restrict__ zw, int SL,
                                          uint32_t* __restrict__ colw, int nColV) {
    int bid = blockIdx.x, t = threadIdx.x;
    if (bid < nbC) {
        int i = bid * 512 + t;
        if (i <= N) cursor[i] = 0;
        if (bid == 0 && t < 64)  // pad row (node N) of each slice = 0
            zw[(size_t)(t >> 4) * SL + (size_t)N * 16 + (t & 15)] = 0u;
    } else if (bid < nbC + 8) {
        int tid = (bid - nbC) * 512 + t;        // 0..4095
        const float* W = (tid & 2048) ? W2 : W1;
        uint16_t* O = (tid & 2048) ? Wf2 : Wf1;
        int q16 = tid & 2047;
        int lane = q16 & 63, n0ks = q16 >> 6;
        int n0 = n0ks >> 2, ks = n0ks & 3;
        int m = lane & 15, quad = lane >> 4;
        int nn = n0 * 16 + m;
        int kkb = ks * 32 + quad * 8;
        uint16_t v[8];
#pragma unroll
        for (int j = 0; j < 8; ++j) v[j] = bf16rne(W[(kkb + j) * 128 + nn]);
        *(short8*)&O[q16 * 8] = *(short8*)v;
    } else if (bid < nbC + 8 + nbZ) {
        int idx = (bid - nbC - 8) * 512 + t;    // nbZ blocks x 512 float4s
        ((float4*)g_out)[idx] = make_float4(0.f, 0.f, 0.f, 0.f);
    } else {
        int idx = (bid - nbC - 8 - nbZ) * 512 + t;  // col pad fill (uint4)
        if (idx < nColV) {
            uint32_t p = ((uint32_t)N & 0xffffu) | ((uint32_t)N << 16);
            ((uint4*)colw)[idx] = make_uint4(p, p, p, p);
        }
    }
}

// ---- gemm body (8 waves, M=128 tile); optional dinv-fold; sliced Y ----
__device__ __forceinline__ void gemm_body(const float* Xf, const uint16_t* Xb,
                                          const uint16_t* __restrict__ Wf,
                                          uint16_t* __restrict__ Y, int nrows,
                                          const int* __restrict__ cnt,  // nullptr -> no fold
                                          uint16_t* Wl, int bid, int t, int ySL) {
    int lane = t & 63, w = t >> 6;
    int row0 = bid * 128;
    for (int c = t; c < 2048; c += 512)
        *(short8*)&Wl[c * 8] = *(const short8*)&Wf[c * 8];
    int m = lane & 15, quad = lane >> 4;
    int arow = row0 + w * 16 + m;
    bool rowok = arow < nrows;
    short8 a[4];
    short8 zer = {0, 0, 0, 0, 0, 0, 0, 0};
    if (Xb) {
        const uint16_t* aptr = Xb + (size_t)arow * 128 + quad * 8;
#pragma unroll
        for (int ks = 0; ks < 4; ++ks)
            a[ks] = rowok ? *(const short8*)(aptr + ks * 32) : zer;
    } else {
        const float* ap = Xf + (size_t)arow * 128 + quad * 8;
#pragma unroll
        for (int ks = 0; ks < 4; ++ks) {
            if (rowok) {
                float4 u0 = *(const float4*)(ap + ks * 32);
                float4 u1 = *(const float4*)(ap + ks * 32 + 4);
                uint32_t q[4];
                q[0] = (uint32_t)bf16rne(u0.x) | ((uint32_t)bf16rne(u0.y) << 16);
                q[1] = (uint32_t)bf16rne(u0.z) | ((uint32_t)bf16rne(u0.w) << 16);
                q[2] = (uint32_t)bf16rne(u1.x) | ((uint32_t)bf16rne(u1.y) << 16);
                q[3] = (uint32_t)bf16rne(u1.z) | ((uint32_t)bf16rne(u1.w) << 16);
                a[ks] = *(short8*)q;
            } else a[ks] = zer;
        }
    }
    __syncthreads();

    f32x4 acc[8];
#pragma unroll
    for (int i = 0; i < 8; ++i) acc[i] = (f32x4){0.f, 0.f, 0.f, 0.f};
#pragma unroll
    for (int ks = 0; ks < 4; ++ks)
#pragma unroll
        for (int n0 = 0; n0 < 8; ++n0) {
            short8 b = *(short8*)&Wl[((n0 * 4 + ks) * 64 + lane) * 8];
            acc[n0] = __builtin_amdgcn_mfma_f32_16x16x32_bf16(a[ks], b, acc[n0], 0, 0, 0);
        }
    __syncthreads();  // all 8 waves done reading Wl; reuse as epilogue buffer

    float dsc[4] = {1.f, 1.f, 1.f, 1.f};
    if (cnt) {
#pragma unroll
        for (int r = 0; r < 4; ++r) {
            int gr = row0 + w * 16 + quad * 4 + r;
            int d = (gr < nrows) ? cnt[gr] : 0;
            dsc[r] = rsqrtf((float)(d + 1));
        }
    }

    uint16_t* Ep = Wl;  // [128][136] view, wave-private 16-row bands
#pragma unroll
    for (int n0 = 0; n0 < 8; ++n0)
#pragma unroll
        for (int r = 0; r < 4; ++r)
            Ep[(w * 16 + quad * 4 + r) * 136 + n0 * 16 + m] = bf16rne(acc[n0][r] * dsc[r]);
    for (int r16 = 0; r16 < 16; ++r16) {
        int row = row0 + w * 16 + r16;
        if (row < nrows) {
            uint32_t v = *(uint32_t*)&Ep[(w * 16 + r16) * 136 + lane * 2];
            // slice (lane>>4) holds ch-pair dword (lane&15) of row
            ((uint32_t*)Y)[(size_t)(lane >> 4) * ySL + (size_t)row * 16 + (lane & 15)] = v;
        }
    }
}

// ---- fill body (512 thr): 4 edges/thread; bucket write (u16) + deg count ----
__device__ __forceinline__ void fill_body(const int* __restrict__ src, const int* __restrict__ dst,
                                          int* __restrict__ cursor, uint16_t* __restrict__ col,
                                          int E, int fb, int t) {
    int base = fb * 2048 + t;
    int d[4], s[4], p[4];
#pragma unroll
    for (int k = 0; k < 4; ++k) {
        int e = base + k * 512;
        d[k] = (e < E) ? dst[e] : -1;
        s[k] = (e < E) ? src[e] : 0;
    }
#pragma unroll
    for (int k = 0; k < 4; ++k) if (d[k] >= 0) p[k] = atomicAdd(&cursor[d[k]], 1);
#pragma unroll
    for (int k = 0; k < 4; ++k)
        if (d[k] >= 0 && p[k] < CAP) col[(size_t)d[k] * CAP + p[k]] = (uint16_t)s[k];
}

// ---- K5: gemm1 (+) fill interleaved ----
__global__ __launch_bounds__(512, 8) void k5(const float* __restrict__ X,
                                             const uint16_t* __restrict__ Wf,
                                             uint16_t* __restrict__ Y, int nrows, int gemmGrid,
                                             const int* __restrict__ src, const int* __restrict__ dst,
                                             int* __restrict__ cursor, uint16_t* __restrict__ col,
                                             int E, int fillGrid, int SL) {
    __shared__ uint16_t Wl[17408];
    int bid = blockIdx.x, t = threadIdx.x;
    int mn = min(gemmGrid, fillGrid), mn2 = 2 * mn;
    int role, idx;
    if (bid < mn2) { role = bid & 1; idx = bid >> 1; }
    else { role = (gemmGrid > fillGrid) ? 0 : 1; idx = bid - mn2 + mn; }
    if (role == 0) gemm_body(X, nullptr, Wf, Y, nrows, nullptr, Wl, idx, t, SL);
    else fill_body(src, dst, cursor, col, E, idx, t);
}

// ---- gemm standalone (layer 2): M=128, 512 thr, dinv fold, sliced Y ----
__global__ __launch_bounds__(512, 8) void gemm2k(const uint16_t* __restrict__ Xb,
                                                 const uint16_t* __restrict__ Wf,
                                                 uint16_t* __restrict__ Y, int nrows,
                                                 const int* __restrict__ cnt, int SL) {
    __shared__ uint16_t Wl[17408];
    gemm_body(nullptr, Xb, Wf, Y, nrows, cnt, Wl, blockIdx.x, threadIdx.x, SL);
}

// ---- agg + fused pool, sliced, wave = 1 node x 4 edge-groups:
//      block -> slice s=(bid%8)>>1 (XCD affinity), 4 nodes/block (1/wave).
//      Group g handles edges 2g,2g+1 of each 8-batch; ids read directly from
//      pre-padded col (pad id = n -> zero row). Cross-group shfl reduce.
//      PS=true: zw rows pre-scaled by dinv (layer 2) ----
template <bool PS>
__global__ __launch_bounds__(256) void aggp(const uint32_t* __restrict__ zw,
                                            const int* __restrict__ cnt,
                                            const uint16_t* __restrict__ col,
                                            const float* __restrict__ bias,
                                            const float* __restrict__ alpha,
                                            const int* __restrict__ batch,
                                            float* __restrict__ gout, int col_off,
                                            uint32_t* __restrict__ z1b,
                                            float* __restrict__ zoutf,
                                            int mode, int n, int SL, int NB) {
    __shared__ int gsh[4];
    __shared__ float red[4][32];
    int bid = blockIdx.x;
    int s = (bid & 7) >> 1;                 // slice (2 XCDs per slice)
    int j = ((bid >> 3) << 1) | (bid & 1);  // node-quad index within slice
    if (j >= NB) return;
    int t = threadIdx.x;
    int wv = t >> 6, lane = t & 63;
    int g = lane >> 4, i = lane & 15;
    int node = j * 4 + wv;
    bool valid = node < n;
    int nd = valid ? node : n;              // row n zero, cnt[n]=0 -> len8=0
    const uint32_t* zs = zw + (size_t)s * SL;
    int deg = cnt[nd];
    float di = rsqrtf((float)(deg + 1));
    uint32_t sv = zs[(uint32_t)nd * 16 + i];
    float selfw = (g == 0) ? (PS ? 1.f : di) : 0.f;  // self only in group 0
    float ax = selfw * bf_lo(sv), ay = selfw * bf_hi(sv);
    float bx = 0.f, by = 0.f;
    int len8 = (min(deg, CAP) + 7) & ~7;    // col pre-padded with id=n
    const uint32_t* colp = (const uint32_t*)(col + (size_t)nd * CAP);
    int e = 0;
    for (; e + 16 <= len8; e += 16) {       // 16-edge volley: 4 edges/lane
        uint32_t c0 = colp[(e >> 1) + g];
        uint32_t c1 = colp[(e >> 1) + 4 + g];
        int i0 = (int)(c0 & 0xffffu), i1 = (int)(c0 >> 16);
        int i2 = (int)(c1 & 0xffffu), i3 = (int)(c1 >> 16);
        uint32_t v0 = zs[(uint32_t)i0 * 16 + i];
        uint32_t v1 = zs[(uint32_t)i1 * 16 + i];
        uint32_t v2 = zs[(uint32_t)i2 * 16 + i];
        uint32_t v3 = zs[(uint32_t)i3 * 16 + i];
        float w0 = PS ? 1.f : rsqrtf((float)(cnt[i0] + 1));
        float w1 = PS ? 1.f : rsqrtf((float)(cnt[i1] + 1));
        float w2 = PS ? 1.f : rsqrtf((float)(cnt[i2] + 1));
        float w3 = PS ? 1.f : rsqrtf((float)(cnt[i3] + 1));
        ax += w0 * bf_lo(v0); ay += w0 * bf_hi(v0);
        bx += w1 * bf_lo(v1); by += w1 * bf_hi(v1);
        ax += w2 * bf_lo(v2); ay += w2 * bf_hi(v2);
        bx += w3 * bf_lo(v3); by += w3 * bf_hi(v3);
    }
    if (e < len8) {                          // one 8-edge tail: 2 edges/lane
        uint32_t c0 = colp[(e >> 1) + g];
        int i0 = (int)(c0 & 0xffffu), i1 = (int)(c0 >> 16);
        uint32_t v0 = zs[(uint32_t)i0 * 16 + i];
        uint32_t v1 = zs[(uint32_t)i1 * 16 + i];
        float w0 = PS ? 1.f : rsqrtf((float)(cnt[i0] + 1));
        float w1 = PS ? 1.f : rsqrtf((float)(cnt[i1] + 1));
        ax += w0 * bf_lo(v0); ay += w0 * bf_hi(v0);
        bx += w1 * bf_lo(v1); by += w1 * bf_hi(v1);
    }
    ax += bx; ay += by;
    // cross-group tree reduce (same i across the 4 groups)
    ax += __shfl_xor(ax, 16); ay += __shfl_xor(ay, 16);
    ax += __shfl_xor(ax, 32); ay += __shfl_xor(ay, 32);
    float2 bb = ((const float2*)bias)[s * 16 + i];
    float2 aa = ((const float2*)alpha)[s * 16 + i];
    float zx = di * ax + bb.x;
    float zy = di * ay + bb.y;
    zx = zx > 0.f ? zx : aa.x * zx;
    zy = zy > 0.f ? zy : aa.y * zy;

    if (valid && g == 0) {
        if (mode == 0) {
            uint32_t pk = (uint32_t)bf16rne(zx) | ((uint32_t)bf16rne(zy) << 16);
            z1b[(size_t)node * 64 + s * 16 + i] = pk;
        } else {
            ((float2*)zoutf)[(size_t)node * 64 + s * 16 + i] = make_float2(zx, zy);
        }
    }

    // ---- pool over the block's 4 nodes ----
    int gr = valid ? batch[node] : -1 - wv;
    if (lane == 0) gsh[wv] = gr;
    __syncthreads();
    bool uni = (gsh[0] == gsh[1]) && (gsh[1] == gsh[2]) && (gsh[2] == gsh[3]);
    float cx = valid ? zx : 0.f, cy = valid ? zy : 0.f;
    if (uni) {
        if (g == 0) { red[wv][2 * i] = cx; red[wv][2 * i + 1] = cy; }
        __syncthreads();
        if (wv == 0 && g == 0) {
            float sx = red[0][2 * i] + red[1][2 * i] + red[2][2 * i] + red[3][2 * i];
            float sy = red[0][2 * i + 1] + red[1][2 * i + 1] + red[2][2 * i + 1] + red[3][2 * i + 1];
            float* base = &gout[(size_t)gsh[0] * 256 + col_off + s * 32 + 2 * i];
            atomicAdd(&base[0], sx);
            atomicAdd(&base[1], sy);
        }
    } else {
        __syncthreads();
        if (valid && g == 0) {
            float* base = &gout[(size_t)gr * 256 + col_off + s * 32 + 2 * i];
            atomicAdd(&base[0], cx);
            atomicAdd(&base[1], cy);
        }
    }
}

extern "C" void kernel_launch(void* const* d_in, const int* in_sizes, int n_in,
                              void* d_out, int out_size, void* d_ws, size_t ws_size,
                              hipStream_t stream) {
    const float* x     = (const float*)d_in[0];
    const int*   eidx  = (const int*)d_in[1];
    const int*   batch = (const int*)d_in[2];
    const float* W1    = (const float*)d_in[3];
    const float* b1    = (const float*)d_in[4];
    const float* W2    = (const float*)d_in[5];
    const float* b2    = (const float*)d_in[6];
    const float* alpha = (const float*)d_in[7];

    const int N = in_sizes[2];
    const int E = in_sizes[1] / 2;
    const int G = (out_size - N * 128) / 256;

    const int* src = eidx;
    const int* dst = eidx + E;

    char* ws = (char*)d_ws;
    size_t off = 0;
    auto alloc = [&](size_t bytes) { void* q = ws + off; off = (off + bytes + 255) & ~(size_t)255; return q; };
    int*      cursor = (int*)alloc((size_t)(N + 1) * 4);
    uint16_t* col    = (uint16_t*)alloc((size_t)N * CAP * 2);
    uint32_t* zw     = (uint32_t*)alloc((size_t)(N + 1) * 128 * 2);  // 4 slices x (N+1) x 64B
    uint32_t* z1b    = (uint32_t*)alloc((size_t)N * 128 * 2);
    uint16_t* Wf1    = (uint16_t*)alloc(128 * 128 * 2);
    uint16_t* Wf2    = (uint16_t*)alloc(128 * 128 * 2);

    float* z_out = (float*)d_out;
    float* g_out = (float*)d_out + (size_t)N * 128;

    const int SL = (N + 1) * 16;               // slice stride in dwords
    int nbC      = (N + 512) / 512;            // cursor zero (N+1 entries)
    int nbZ      = (G * 256 / 4 + 511) / 512;  // g_out zero (float4)
    int nColV    = (N * CAP * 2) / 16;         // col fill in uint4s
    int nbP      = (nColV + 511) / 512;
    int fillGrid = (E + 2047) / 2048;          // 4 edges/thread x 512
    int gemmGrid = (N + 127) / 128;            // M=128 tiles x 512 thr
    int NB       = (N + 3) / 4;                // node-quads per slice
    int aggGrid  = 8 * ((NB + 1) / 2);

    k0<<<nbC + 8 + nbZ + nbP, 512, 0, stream>>>(cursor, nbC, N, W1, W2, Wf1, Wf2,
                                                g_out, nbZ, zw, SL, (uint32_t*)col, nColV);
    k5<<<gemmGrid + fillGrid, 512, 0, stream>>>(x, Wf1, (uint16_t*)zw, N, gemmGrid,
                                                src, dst, cursor, col, E, fillGrid, SL);
    aggp<false><<<aggGrid, 256, 0, stream>>>(zw, cursor, col, b1, alpha, batch,
                                             g_out, 0, z1b, nullptr, 0, N, SL, NB);
    gemm2k<<<gemmGrid, 512, 0, stream>>>((const uint16_t*)z1b, Wf2, (uint16_t*)zw, N, cursor, SL);
    aggp<true><<<aggGrid, 256, 0, stream>>>(zw, cursor, col, b2, alpha, batch,
                                            g_out, 128, nullptr, z_out, 1, N, SL, NB);
}

// Round 8
// 226.800 us; speedup vs baseline: 1.3892x; 1.3892x over previous
//
#include <hip/hip_runtime.h>
#include <stdint.h>

// ---------------------------------------------------------------------------
// GCN 2-layer. R18: aggp = R15 winner verbatim (1 node/wave, 8-wide batch,
// pad-to-8 zero row, VGPR ~20). NEW: zscale pass after k5 folds dinv[row] into
// zw1 rows (streaming 12.8MB, ~5us) so BOTH aggp passes run PS=true: no
// scattered cnt[s] gathers (-33% L2 line transactions/edge, the confirmed
// bottleneck per R17's 2x-transactions = 2x-time result) and no rsqrt chain.
// 6 dispatches: k0 -> k5(gemm1(+)fill) -> zscale -> aggp<true> ->
// gemm2k(dinv-fold) -> aggp<true>.
// ---------------------------------------------------------------------------

#define CAP 96

typedef __attribute__((ext_vector_type(8))) short short8;
typedef __attribute__((ext_vector_type(4))) float f32x4;

__device__ __forceinline__ uint16_t bf16rne(float f) {
    uint32_t u = __float_as_uint(f);
    uint32_t r = (u + 0x7fffu + ((u >> 16) & 1u)) >> 16;
    return (uint16_t)r;
}
__device__ __forceinline__ float bf_lo(uint32_t v) { return __uint_as_float(v << 16); }
__device__ __forceinline__ float bf_hi(uint32_t v) { return __uint_as_float(v & 0xffff0000u); }

// ---- K0 (512 thr): zero cursor(N+1) + zw pad row | prep_w | zero g_out ----
__global__ __launch_bounds__(512) void k0(int* __restrict__ cursor, int nbC, int N,
                                          const float* __restrict__ W1,
                                          const float* __restrict__ W2,
                                          uint16_t* __restrict__ Wf1,
                                          uint16_t* __restrict__ Wf2,
                                          float* __restrict__ g_out, int nbZ,
                                          uint32_t* __restrict__ zw) {
    int bid = blockIdx.x, t = threadIdx.x;
    if (bid < nbC) {
        int i = bid * 512 + t;
        if (i <= N) cursor[i] = 0;
        if (bid == 0 && t < 64) zw[(size_t)N * 64 + t] = 0u;  // pad row = 0
    } else if (bid < nbC + 8) {
        int tid = (bid - nbC) * 512 + t;        // 0..4095
        const float* W = (tid & 2048) ? W2 : W1;
        uint16_t* O = (tid & 2048) ? Wf2 : Wf1;
        int q16 = tid & 2047;
        int lane = q16 & 63, n0ks = q16 >> 6;
        int n0 = n0ks >> 2, ks = n0ks & 3;
        int m = lane & 15, quad = lane >> 4;
        int nn = n0 * 16 + m;
        int kkb = ks * 32 + quad * 8;
        uint16_t v[8];
#pragma unroll
        for (int j = 0; j < 8; ++j) v[j] = bf16rne(W[(kkb + j) * 128 + nn]);
        *(short8*)&O[q16 * 8] = *(short8*)v;
    } else {
        int idx = (bid - nbC - 8) * 512 + t;    // nbZ blocks x 512 float4s
        ((float4*)g_out)[idx] = make_float4(0.f, 0.f, 0.f, 0.f);
    }
}

// ---- gemm body (8 waves, M=128 tile); optional dinv-fold epilogue ----
__device__ __forceinline__ void gemm_body(const float* Xf, const uint16_t* Xb,
                                          const uint16_t* __restrict__ Wf,
                                          uint16_t* __restrict__ Y, int nrows,
                                          const int* __restrict__ cnt,  // nullptr -> no fold
                                          uint16_t* Wl, int bid, int t) {
    int lane = t & 63, w = t >> 6;
    int row0 = bid * 128;
    for (int c = t; c < 2048; c += 512)
        *(short8*)&Wl[c * 8] = *(const short8*)&Wf[c * 8];
    int m = lane & 15, quad = lane >> 4;
    int arow = row0 + w * 16 + m;
    bool rowok = arow < nrows;
    short8 a[4];
    short8 zer = {0, 0, 0, 0, 0, 0, 0, 0};
    if (Xb) {
        const uint16_t* aptr = Xb + (size_t)arow * 128 + quad * 8;
#pragma unroll
        for (int ks = 0; ks < 4; ++ks)
            a[ks] = rowok ? *(const short8*)(aptr + ks * 32) : zer;
    } else {
        const float* ap = Xf + (size_t)arow * 128 + quad * 8;
#pragma unroll
        for (int ks = 0; ks < 4; ++ks) {
            if (rowok) {
                float4 u0 = *(const float4*)(ap + ks * 32);
                float4 u1 = *(const float4*)(ap + ks * 32 + 4);
                uint32_t q[4];
                q[0] = (uint32_t)bf16rne(u0.x) | ((uint32_t)bf16rne(u0.y) << 16);
                q[1] = (uint32_t)bf16rne(u0.z) | ((uint32_t)bf16rne(u0.w) << 16);
                q[2] = (uint32_t)bf16rne(u1.x) | ((uint32_t)bf16rne(u1.y) << 16);
                q[3] = (uint32_t)bf16rne(u1.z) | ((uint32_t)bf16rne(u1.w) << 16);
                a[ks] = *(short8*)q;
            } else a[ks] = zer;
        }
    }
    __syncthreads();

    f32x4 acc[8];
#pragma unroll
    for (int i = 0; i < 8; ++i) acc[i] = (f32x4){0.f, 0.f, 0.f, 0.f};
#pragma unroll
    for (int ks = 0; ks < 4; ++ks)
#pragma unroll
        for (int n0 = 0; n0 < 8; ++n0) {
            short8 b = *(short8*)&Wl[((n0 * 4 + ks) * 64 + lane) * 8];
            acc[n0] = __builtin_amdgcn_mfma_f32_16x16x32_bf16(a[ks], b, acc[n0], 0, 0, 0);
        }
    __syncthreads();  // all 8 waves done reading Wl; reuse as epilogue buffer

    // per-lane output rows are (quad*4 + r); fold dinv there if requested
    float dsc[4] = {1.f, 1.f, 1.f, 1.f};
    if (cnt) {
#pragma unroll
        for (int r = 0; r < 4; ++r) {
            int gr = row0 + w * 16 + quad * 4 + r;
            int d = (gr < nrows) ? cnt[gr] : 0;
            dsc[r] = rsqrtf((float)(d + 1));
        }
    }

    uint16_t* Ep = Wl;  // [128][136] view, wave-private 16-row bands
#pragma unroll
    for (int n0 = 0; n0 < 8; ++n0)
#pragma unroll
        for (int r = 0; r < 4; ++r)
            Ep[(w * 16 + quad * 4 + r) * 136 + n0 * 16 + m] = bf16rne(acc[n0][r] * dsc[r]);
    for (int r16 = 0; r16 < 16; ++r16) {
        int row = row0 + w * 16 + r16;
        if (row < nrows) {
            uint32_t v = *(uint32_t*)&Ep[(w * 16 + r16) * 136 + lane * 2];
            ((uint32_t*)Y)[(size_t)row * 64 + lane] = v;
        }
    }
}

// ---- fill body (512 thr): 4 edges/thread; bucket write (u16) + deg count ----
__device__ __forceinline__ void fill_body(const int* __restrict__ src, const int* __restrict__ dst,
                                          int* __restrict__ cursor, uint16_t* __restrict__ col,
                                          int E, int fb, int t) {
    int base = fb * 2048 + t;
    int d[4], s[4], p[4];
#pragma unroll
    for (int k = 0; k < 4; ++k) {
        int e = base + k * 512;
        d[k] = (e < E) ? dst[e] : -1;
        s[k] = (e < E) ? src[e] : 0;
    }
#pragma unroll
    for (int k = 0; k < 4; ++k) if (d[k] >= 0) p[k] = atomicAdd(&cursor[d[k]], 1);
#pragma unroll
    for (int k = 0; k < 4; ++k)
        if (d[k] >= 0 && p[k] < CAP) col[(size_t)d[k] * CAP + p[k]] = (uint16_t)s[k];
}

// ---- K5: gemm1 (+) fill interleaved ----
__global__ __launch_bounds__(512, 8) void k5(const float* __restrict__ X,
                                             const uint16_t* __restrict__ Wf,
                                             uint16_t* __restrict__ Y, int nrows, int gemmGrid,
                                             const int* __restrict__ src, const int* __restrict__ dst,
                                             int* __restrict__ cursor, uint16_t* __restrict__ col,
                                             int E, int fillGrid) {
    __shared__ uint16_t Wl[17408];
    int bid = blockIdx.x, t = threadIdx.x;
    int mn = min(gemmGrid, fillGrid), mn2 = 2 * mn;
    int role, idx;
    if (bid < mn2) { role = bid & 1; idx = bid >> 1; }
    else { role = (gemmGrid > fillGrid) ? 0 : 1; idx = bid - mn2 + mn; }
    if (role == 0) gemm_body(X, nullptr, Wf, Y, nrows, nullptr, Wl, idx, t);
    else fill_body(src, dst, cursor, col, E, idx, t);
}

// ---- gemm standalone (layer 2): M=128, 512 thr, dinv folded into output ----
__global__ __launch_bounds__(512, 8) void gemm2k(const uint16_t* __restrict__ Xb,
                                                 const uint16_t* __restrict__ Wf,
                                                 uint16_t* __restrict__ Y, int nrows,
                                                 const int* __restrict__ cnt) {
    __shared__ uint16_t Wl[17408];
    gemm_body(nullptr, Xb, Wf, Y, nrows, cnt, Wl, blockIdx.x, threadIdx.x);
}

// ---- zscale: zw1[row] *= dinv[row] in place (bf16 pairs); after fill done ----
__global__ __launch_bounds__(512) void zscale(uint32_t* __restrict__ zw,
                                              const int* __restrict__ cnt, int ndw) {
    int idx = blockIdx.x * 512 + threadIdx.x;   // dword index
    if (idx >= ndw) return;
    int row = idx >> 6;
    float di = rsqrtf((float)(cnt[row] + 1));
    uint32_t v = zw[idx];
    float lo = bf_lo(v) * di, hi = bf_hi(v) * di;
    zw[idx] = (uint32_t)bf16rne(lo) | ((uint32_t)bf16rne(hi) << 16);
}

// ---- agg + fused pool (R15 winner): 4 waves = 4 nodes; bucket in 1 VGPR,
//      readlane -> SGPR-addressed gathers; 8-wide batch loop; pad-to-8 via
//      zero row (id=n). PS=true: zw rows pre-scaled by dinv -> no cnt
//      gathers / rsqrt / cvt per edge ----
template <bool PS>
__global__ __launch_bounds__(256) void aggp(const uint32_t* __restrict__ zw,
                                            const int* __restrict__ cnt,
                                            const uint16_t* __restrict__ col,
                                            const float* __restrict__ bias,
                                            const float* __restrict__ alpha,
                                            const int* __restrict__ batch,
                                            float* __restrict__ gout, int col_off,
                                            uint32_t* __restrict__ z1b,
                                            float* __restrict__ zoutf,
                                            int mode, int n) {
    __shared__ int gsh[4];
    __shared__ float red[4][128];
    int wv = threadIdx.x >> 6;
    int lane = threadIdx.x & 63;
    int node = blockIdx.x * 4 + wv;
    bool valid = node < n;
    int nc = __builtin_amdgcn_readfirstlane(valid ? node : (n - 1));
    int c = lane * 2;
    int deg = cnt[nc];
    float di = rsqrtf((float)(deg + 1));
    uint32_t sv = zw[(size_t)nc * 64 + lane];
    // self term: PS rows already carry dinv[nc]; non-PS needs explicit di
    float sw = PS ? 1.f : di;
    float ax = sw * bf_lo(sv), ay = sw * bf_hi(sv);
    float bx = 0.f, by = 0.f;
    int len = min(deg, CAP);
    int len8 = (len + 7) & ~7;   // padded length (pads -> id n, zero row)
    // whole bucket (96 x u16 = 48 x u32) into one VGPR: lane l holds ids 2l,2l+1
    const uint32_t* cbu = (const uint32_t*)(col + (size_t)nc * CAP);
    uint32_t cc = cbu[lane < 48 ? lane : 0];
    for (int e = 0; e < len8; e += 8) {
        int h = e >> 1;
        uint32_t q0 = (uint32_t)__builtin_amdgcn_readlane((int)cc, h);
        uint32_t q1 = (uint32_t)__builtin_amdgcn_readlane((int)cc, h + 1);
        uint32_t q2 = (uint32_t)__builtin_amdgcn_readlane((int)cc, h + 2);
        uint32_t q3 = (uint32_t)__builtin_amdgcn_readlane((int)cc, h + 3);
        int s0 = (e + 0 < len) ? (int)(q0 & 0xffffu) : n;
        int s1 = (e + 1 < len) ? (int)(q0 >> 16)     : n;
        int s2 = (e + 2 < len) ? (int)(q1 & 0xffffu) : n;
        int s3 = (e + 3 < len) ? (int)(q1 >> 16)     : n;
        int s4 = (e + 4 < len) ? (int)(q2 & 0xffffu) : n;
        int s5 = (e + 5 < len) ? (int)(q2 >> 16)     : n;
        int s6 = (e + 6 < len) ? (int)(q3 & 0xffffu) : n;
        int s7 = (e + 7 < len) ? (int)(q3 >> 16)     : n;
        uint32_t v0 = zw[(size_t)s0 * 64 + lane];
        uint32_t v1 = zw[(size_t)s1 * 64 + lane];
        uint32_t v2 = zw[(size_t)s2 * 64 + lane];
        uint32_t v3 = zw[(size_t)s3 * 64 + lane];
        uint32_t v4 = zw[(size_t)s4 * 64 + lane];
        uint32_t v5 = zw[(size_t)s5 * 64 + lane];
        uint32_t v6 = zw[(size_t)s6 * 64 + lane];
        uint32_t v7 = zw[(size_t)s7 * 64 + lane];
        float w0 = PS ? 1.f : rsqrtf((float)(cnt[s0] + 1));
        float w1 = PS ? 1.f : rsqrtf((float)(cnt[s1] + 1));
        float w2 = PS ? 1.f : rsqrtf((float)(cnt[s2] + 1));
        float w3 = PS ? 1.f : rsqrtf((float)(cnt[s3] + 1));
        float w4 = PS ? 1.f : rsqrtf((float)(cnt[s4] + 1));
        float w5 = PS ? 1.f : rsqrtf((float)(cnt[s5] + 1));
        float w6 = PS ? 1.f : rsqrtf((float)(cnt[s6] + 1));
        float w7 = PS ? 1.f : rsqrtf((float)(cnt[s7] + 1));
        ax += w0 * bf_lo(v0); ay += w0 * bf_hi(v0);
        bx += w1 * bf_lo(v1); by += w1 * bf_hi(v1);
        ax += w2 * bf_lo(v2); ay += w2 * bf_hi(v2);
        bx += w3 * bf_lo(v3); by += w3 * bf_hi(v3);
        ax += w4 * bf_lo(v4); ay += w4 * bf_hi(v4);
        bx += w5 * bf_lo(v5); by += w5 * bf_hi(v5);
        ax += w6 * bf_lo(v6); ay += w6 * bf_hi(v6);
        bx += w7 * bf_lo(v7); by += w7 * bf_hi(v7);
    }
    ax += bx; ay += by;
    float zx = di * ax + bias[c];
    float zy = di * ay + bias[c + 1];
    float px = alpha[c], py = alpha[c + 1];
    zx = zx > 0.f ? zx : px * zx;
    zy = zy > 0.f ? zy : py * zy;

    if (valid) {
        if (mode == 0) {
            uint32_t pk = (uint32_t)bf16rne(zx) | ((uint32_t)bf16rne(zy) << 16);
            z1b[(size_t)nc * 64 + lane] = pk;
        } else {
            ((float2*)zoutf)[(size_t)nc * 64 + lane] = make_float2(zx, zy);
        }
    }

    int g = batch[nc];
    float cx = valid ? zx : 0.f, cy = valid ? zy : 0.f;
    if (lane == 0) gsh[wv] = valid ? g : -1 - wv;
    __syncthreads();
    bool uni = (gsh[0] == gsh[1]) && (gsh[1] == gsh[2]) && (gsh[2] == gsh[3]);
    if (uni) {
        red[wv][c] = cx; red[wv][c + 1] = cy;
        __syncthreads();
        if (wv == 0) {
            float sx = red[0][c] + red[1][c] + red[2][c] + red[3][c];
            float sy = red[0][c + 1] + red[1][c + 1] + red[2][c + 1] + red[3][c + 1];
            float* base = &gout[(size_t)g * 256 + col_off];
            atomicAdd(&base[c], sx);
            atomicAdd(&base[c + 1], sy);
        }
    } else {
        __syncthreads();
        if (valid) {
            float* base = &gout[(size_t)g * 256 + col_off];
            atomicAdd(&base[c], cx);
            atomicAdd(&base[c + 1], cy);
        }
    }
}

extern "C" void kernel_launch(void* const* d_in, const int* in_sizes, int n_in,
                              void* d_out, int out_size, void* d_ws, size_t ws_size,
                              hipStream_t stream) {
    const float* x     = (const float*)d_in[0];
    const int*   eidx  = (const int*)d_in[1];
    const int*   batch = (const int*)d_in[2];
    const float* W1    = (const float*)d_in[3];
    const float* b1    = (const float*)d_in[4];
    const float* W2    = (const float*)d_in[5];
    const float* b2    = (const float*)d_in[6];
    const float* alpha = (const float*)d_in[7];

    const int N = in_sizes[2];
    const int E = in_sizes[1] / 2;
    const int G = (out_size - N * 128) / 256;

    const int* src = eidx;
    const int* dst = eidx + E;

    char* ws = (char*)d_ws;
    size_t off = 0;
    auto alloc = [&](size_t bytes) { void* q = ws + off; off = (off + bytes + 255) & ~(size_t)255; return q; };
    int*      cursor = (int*)alloc((size_t)(N + 1) * 4);
    uint16_t* col    = (uint16_t*)alloc((size_t)N * CAP * 2);
    uint32_t* zw     = (uint32_t*)alloc((size_t)(N + 1) * 128 * 2);  // +1 pad row (zeroed)
    uint32_t* z1b    = (uint32_t*)alloc((size_t)N * 128 * 2);
    uint16_t* Wf1    = (uint16_t*)alloc(128 * 128 * 2);
    uint16_t* Wf2    = (uint16_t*)alloc(128 * 128 * 2);

    float* z_out = (float*)d_out;
    float* g_out = (float*)d_out + (size_t)N * 128;

    int nbC      = (N + 512) / 512;            // cursor zero (N+1 entries)
    int nbZ      = (G * 256 / 4 + 511) / 512;  // g_out zero (float4)
    int fillGrid = (E + 2047) / 2048;          // 4 edges/thread x 512
    int gemmGrid = (N + 127) / 128;            // M=128 tiles x 512 thr
    int aggGrid  = (N + 3) / 4;
    int ndw      = N * 64;                     // zscale dwords
    int zsGrid   = (ndw + 511) / 512;

    k0<<<nbC + 8 + nbZ, 512, 0, stream>>>(cursor, nbC, N, W1, W2, Wf1, Wf2, g_out, nbZ, zw);
    k5<<<gemmGrid + fillGrid, 512, 0, stream>>>(x, Wf1, (uint16_t*)zw, N, gemmGrid,
                                                src, dst, cursor, col, E, fillGrid);
    zscale<<<zsGrid, 512, 0, stream>>>(zw, cursor, ndw);
    aggp<true><<<aggGrid, 256, 0, stream>>>(zw, cursor, col, b1, alpha, batch,
                                            g_out, 0, z1b, nullptr, 0, N);
    gemm2k<<<gemmGrid, 512, 0, stream>>>((const uint16_t*)z1b, Wf2, (uint16_t*)zw, N, cursor);
    aggp<true><<<aggGrid, 256, 0, stream>>>(zw, cursor, col, b2, alpha, batch,
                                            g_out, 128, nullptr, z_out, 1, N);
}

// Round 9
// 210.868 us; speedup vs baseline: 1.4942x; 1.0756x over previous
//
#include <hip/hip_runtime.h>
#include <stdint.h>

// ---------------------------------------------------------------------------
// GCN 2-layer. R19: (a) aggp blocks cover 16 nodes (4 waves x 4 nodes serially
// per wave): pool atomics 1.6M -> 0.4M per pass (they were ~40% of aggp's
// transaction budget), block-uniform graph check via sorted batch (2 s_loads),
// 4 node-prologues batched into one latency episode. Per-node 8-wide gather
// loop kept verbatim (R15 winner). (b) k5 fill 2 edges/thread (782 blocks):
// halves the slowest fill block = k5's tail (all blocks resident from t=0).
// 6 dispatches: k0 -> k5(gemm1(+)fill) -> zscale -> aggp<true> ->
// gemm2k(dinv-fold) -> aggp<true>.
// ---------------------------------------------------------------------------

#define CAP 96

typedef __attribute__((ext_vector_type(8))) short short8;
typedef __attribute__((ext_vector_type(4))) float f32x4;

__device__ __forceinline__ uint16_t bf16rne(float f) {
    uint32_t u = __float_as_uint(f);
    uint32_t r = (u + 0x7fffu + ((u >> 16) & 1u)) >> 16;
    return (uint16_t)r;
}
__device__ __forceinline__ float bf_lo(uint32_t v) { return __uint_as_float(v << 16); }
__device__ __forceinline__ float bf_hi(uint32_t v) { return __uint_as_float(v & 0xffff0000u); }

// ---- K0 (512 thr): zero cursor(N+1) + zw pad row | prep_w | zero g_out ----
__global__ __launch_bounds__(512) void k0(int* __restrict__ cursor, int nbC, int N,
                                          const float* __restrict__ W1,
                                          const float* __restrict__ W2,
                                          uint16_t* __restrict__ Wf1,
                                          uint16_t* __restrict__ Wf2,
                                          float* __restrict__ g_out, int nbZ,
                                          uint32_t* __restrict__ zw) {
    int bid = blockIdx.x, t = threadIdx.x;
    if (bid < nbC) {
        int i = bid * 512 + t;
        if (i <= N) cursor[i] = 0;
        if (bid == 0 && t < 64) zw[(size_t)N * 64 + t] = 0u;  // pad row = 0
    } else if (bid < nbC + 8) {
        int tid = (bid - nbC) * 512 + t;        // 0..4095
        const float* W = (tid & 2048) ? W2 : W1;
        uint16_t* O = (tid & 2048) ? Wf2 : Wf1;
        int q16 = tid & 2047;
        int lane = q16 & 63, n0ks = q16 >> 6;
        int n0 = n0ks >> 2, ks = n0ks & 3;
        int m = lane & 15, quad = lane >> 4;
        int nn = n0 * 16 + m;
        int kkb = ks * 32 + quad * 8;
        uint16_t v[8];
#pragma unroll
        for (int j = 0; j < 8; ++j) v[j] = bf16rne(W[(kkb + j) * 128 + nn]);
        *(short8*)&O[q16 * 8] = *(short8*)v;
    } else {
        int idx = (bid - nbC - 8) * 512 + t;    // nbZ blocks x 512 float4s
        ((float4*)g_out)[idx] = make_float4(0.f, 0.f, 0.f, 0.f);
    }
}

// ---- gemm body (8 waves, M=128 tile); optional dinv-fold epilogue ----
__device__ __forceinline__ void gemm_body(const float* Xf, const uint16_t* Xb,
                                          const uint16_t* __restrict__ Wf,
                                          uint16_t* __restrict__ Y, int nrows,
                                          const int* __restrict__ cnt,  // nullptr -> no fold
                                          uint16_t* Wl, int bid, int t) {
    int lane = t & 63, w = t >> 6;
    int row0 = bid * 128;
    for (int c = t; c < 2048; c += 512)
        *(short8*)&Wl[c * 8] = *(const short8*)&Wf[c * 8];
    int m = lane & 15, quad = lane >> 4;
    int arow = row0 + w * 16 + m;
    bool rowok = arow < nrows;
    short8 a[4];
    short8 zer = {0, 0, 0, 0, 0, 0, 0, 0};
    if (Xb) {
        const uint16_t* aptr = Xb + (size_t)arow * 128 + quad * 8;
#pragma unroll
        for (int ks = 0; ks < 4; ++ks)
            a[ks] = rowok ? *(const short8*)(aptr + ks * 32) : zer;
    } else {
        const float* ap = Xf + (size_t)arow * 128 + quad * 8;
#pragma unroll
        for (int ks = 0; ks < 4; ++ks) {
            if (rowok) {
                float4 u0 = *(const float4*)(ap + ks * 32);
                float4 u1 = *(const float4*)(ap + ks * 32 + 4);
                uint32_t q[4];
                q[0] = (uint32_t)bf16rne(u0.x) | ((uint32_t)bf16rne(u0.y) << 16);
                q[1] = (uint32_t)bf16rne(u0.z) | ((uint32_t)bf16rne(u0.w) << 16);
                q[2] = (uint32_t)bf16rne(u1.x) | ((uint32_t)bf16rne(u1.y) << 16);
                q[3] = (uint32_t)bf16rne(u1.z) | ((uint32_t)bf16rne(u1.w) << 16);
                a[ks] = *(short8*)q;
            } else a[ks] = zer;
        }
    }
    __syncthreads();

    f32x4 acc[8];
#pragma unroll
    for (int i = 0; i < 8; ++i) acc[i] = (f32x4){0.f, 0.f, 0.f, 0.f};
#pragma unroll
    for (int ks = 0; ks < 4; ++ks)
#pragma unroll
        for (int n0 = 0; n0 < 8; ++n0) {
            short8 b = *(short8*)&Wl[((n0 * 4 + ks) * 64 + lane) * 8];
            acc[n0] = __builtin_amdgcn_mfma_f32_16x16x32_bf16(a[ks], b, acc[n0], 0, 0, 0);
        }
    __syncthreads();  // all 8 waves done reading Wl; reuse as epilogue buffer

    // per-lane output rows are (quad*4 + r); fold dinv there if requested
    float dsc[4] = {1.f, 1.f, 1.f, 1.f};
    if (cnt) {
#pragma unroll
        for (int r = 0; r < 4; ++r) {
            int gr = row0 + w * 16 + quad * 4 + r;
            int d = (gr < nrows) ? cnt[gr] : 0;
            dsc[r] = rsqrtf((float)(d + 1));
        }
    }

    uint16_t* Ep = Wl;  // [128][136] view, wave-private 16-row bands
#pragma unroll
    for (int n0 = 0; n0 < 8; ++n0)
#pragma unroll
        for (int r = 0; r < 4; ++r)
            Ep[(w * 16 + quad * 4 + r) * 136 + n0 * 16 + m] = bf16rne(acc[n0][r] * dsc[r]);
    for (int r16 = 0; r16 < 16; ++r16) {
        int row = row0 + w * 16 + r16;
        if (row < nrows) {
            uint32_t v = *(uint32_t*)&Ep[(w * 16 + r16) * 136 + lane * 2];
            ((uint32_t*)Y)[(size_t)row * 64 + lane] = v;
        }
    }
}

// ---- fill body (512 thr): 2 edges/thread; bucket write (u16) + deg count ----
__device__ __forceinline__ void fill_body(const int* __restrict__ src, const int* __restrict__ dst,
                                          int* __restrict__ cursor, uint16_t* __restrict__ col,
                                          int E, int fb, int t) {
    int base = fb * 1024 + t;
    int d[2], s[2], p[2];
#pragma unroll
    for (int k = 0; k < 2; ++k) {
        int e = base + k * 512;
        d[k] = (e < E) ? dst[e] : -1;
        s[k] = (e < E) ? src[e] : 0;
    }
#pragma unroll
    for (int k = 0; k < 2; ++k) if (d[k] >= 0) p[k] = atomicAdd(&cursor[d[k]], 1);
#pragma unroll
    for (int k = 0; k < 2; ++k)
        if (d[k] >= 0 && p[k] < CAP) col[(size_t)d[k] * CAP + p[k]] = (uint16_t)s[k];
}

// ---- K5: gemm1 (+) fill interleaved ----
__global__ __launch_bounds__(512, 8) void k5(const float* __restrict__ X,
                                             const uint16_t* __restrict__ Wf,
                                             uint16_t* __restrict__ Y, int nrows, int gemmGrid,
                                             const int* __restrict__ src, const int* __restrict__ dst,
                                             int* __restrict__ cursor, uint16_t* __restrict__ col,
                                             int E, int fillGrid) {
    __shared__ uint16_t Wl[17408];
    int bid = blockIdx.x, t = threadIdx.x;
    int mn = min(gemmGrid, fillGrid), mn2 = 2 * mn;
    int role, idx;
    if (bid < mn2) { role = bid & 1; idx = bid >> 1; }
    else { role = (gemmGrid > fillGrid) ? 0 : 1; idx = bid - mn2 + mn; }
    if (role == 0) gemm_body(X, nullptr, Wf, Y, nrows, nullptr, Wl, idx, t);
    else fill_body(src, dst, cursor, col, E, idx, t);
}

// ---- gemm standalone (layer 2): M=128, 512 thr, dinv folded into output ----
__global__ __launch_bounds__(512, 8) void gemm2k(const uint16_t* __restrict__ Xb,
                                                 const uint16_t* __restrict__ Wf,
                                                 uint16_t* __restrict__ Y, int nrows,
                                                 const int* __restrict__ cnt) {
    __shared__ uint16_t Wl[17408];
    gemm_body(nullptr, Xb, Wf, Y, nrows, cnt, Wl, blockIdx.x, threadIdx.x);
}

// ---- zscale: zw1[row] *= dinv[row] in place (bf16 pairs); after fill done ----
__global__ __launch_bounds__(512) void zscale(uint32_t* __restrict__ zw,
                                              const int* __restrict__ cnt, int ndw) {
    int idx = blockIdx.x * 512 + threadIdx.x;   // dword index
    if (idx >= ndw) return;
    int row = idx >> 6;
    float di = rsqrtf((float)(cnt[row] + 1));
    uint32_t v = zw[idx];
    float lo = bf_lo(v) * di, hi = bf_hi(v) * di;
    zw[idx] = (uint32_t)bf16rne(lo) | ((uint32_t)bf16rne(hi) << 16);
}

// ---- agg + fused pool: 16 nodes/block, 4 waves x 4 nodes serially per wave.
//      Per node: R15 8-wide SGPR-addressed gather loop, pad-to-8 zero row.
//      Pool: wave-level running sum -> LDS cross-wave -> 128 atomics / 16
//      nodes (4x fewer). Uniformity via sorted batch: batch[first]==batch[last].
//      PS=true: zw rows pre-scaled by dinv -> no cnt gathers / rsqrt ----
template <bool PS>
__global__ __launch_bounds__(256) void aggp(const uint32_t* __restrict__ zw,
                                            const int* __restrict__ cnt,
                                            const uint16_t* __restrict__ col,
                                            const float* __restrict__ bias,
                                            const float* __restrict__ alpha,
                                            const int* __restrict__ batch,
                                            float* __restrict__ gout, int col_off,
                                            uint32_t* __restrict__ z1b,
                                            float* __restrict__ zoutf,
                                            int mode, int n) {
    __shared__ float red[4][128];
    int wv = threadIdx.x >> 6;
    int lane = threadIdx.x & 63;
    int c = lane * 2;
    int b0 = blockIdx.x * 16;
    int base = b0 + wv * 4;
    // sorted batch -> block graph-uniform iff first==last (valid-clamped)
    int g0 = batch[min(b0, n - 1)];
    int gL = batch[min(b0 + 15, n - 1)];
    bool uni = (g0 == gL);
    float bsx = bias[c], bsy = bias[c + 1];
    float pax = alpha[c], pay = alpha[c + 1];

    // batched prologue: 4 nodes' deg (s_load), self row, bucket regs
    int nd[4], dg[4];
    uint32_t sv[4], cc[4];
#pragma unroll
    for (int q = 0; q < 4; ++q) {
        int node = base + q;
        nd[q] = (node < n) ? node : n;  // pad row: zw row n = 0, cnt[n] = 0
        dg[q] = cnt[nd[q]];
        sv[q] = zw[(size_t)nd[q] * 64 + lane];
        cc[q] = ((const uint32_t*)(col + (size_t)nd[q] * CAP))[lane < 48 ? lane : 0];
    }

    float psx = 0.f, psy = 0.f;         // wave pool partial
#pragma unroll
    for (int q = 0; q < 4; ++q) {
        int node = base + q;
        bool valid = node < n;
        float di = rsqrtf((float)(dg[q] + 1));
        float sw = PS ? 1.f : di;
        float ax = sw * bf_lo(sv[q]), ay = sw * bf_hi(sv[q]);
        float bx = 0.f, by = 0.f;
        int len = min(dg[q], CAP);
        int len8 = (len + 7) & ~7;
        for (int e = 0; e < len8; e += 8) {
            int h = e >> 1;
            uint32_t q0 = (uint32_t)__builtin_amdgcn_readlane((int)cc[q], h);
            uint32_t q1 = (uint32_t)__builtin_amdgcn_readlane((int)cc[q], h + 1);
            uint32_t q2 = (uint32_t)__builtin_amdgcn_readlane((int)cc[q], h + 2);
            uint32_t q3 = (uint32_t)__builtin_amdgcn_readlane((int)cc[q], h + 3);
            int s0 = (e + 0 < len) ? (int)(q0 & 0xffffu) : n;
            int s1 = (e + 1 < len) ? (int)(q0 >> 16)     : n;
            int s2 = (e + 2 < len) ? (int)(q1 & 0xffffu) : n;
            int s3 = (e + 3 < len) ? (int)(q1 >> 16)     : n;
            int s4 = (e + 4 < len) ? (int)(q2 & 0xffffu) : n;
            int s5 = (e + 5 < len) ? (int)(q2 >> 16)     : n;
            int s6 = (e + 6 < len) ? (int)(q3 & 0xffffu) : n;
            int s7 = (e + 7 < len) ? (int)(q3 >> 16)     : n;
            uint32_t v0 = zw[(size_t)s0 * 64 + lane];
            uint32_t v1 = zw[(size_t)s1 * 64 + lane];
            uint32_t v2 = zw[(size_t)s2 * 64 + lane];
            uint32_t v3 = zw[(size_t)s3 * 64 + lane];
            uint32_t v4 = zw[(size_t)s4 * 64 + lane];
            uint32_t v5 = zw[(size_t)s5 * 64 + lane];
            uint32_t v6 = zw[(size_t)s6 * 64 + lane];
            uint32_t v7 = zw[(size_t)s7 * 64 + lane];
            float w0 = PS ? 1.f : rsqrtf((float)(cnt[s0] + 1));
            float w1 = PS ? 1.f : rsqrtf((float)(cnt[s1] + 1));
            float w2 = PS ? 1.f : rsqrtf((float)(cnt[s2] + 1));
            float w3 = PS ? 1.f : rsqrtf((float)(cnt[s3] + 1));
            float w4 = PS ? 1.f : rsqrtf((float)(cnt[s4] + 1));
            float w5 = PS ? 1.f : rsqrtf((float)(cnt[s5] + 1));
            float w6 = PS ? 1.f : rsqrtf((float)(cnt[s6] + 1));
            float w7 = PS ? 1.f : rsqrtf((float)(cnt[s7] + 1));
            ax += w0 * bf_lo(v0); ay += w0 * bf_hi(v0);
            bx += w1 * bf_lo(v1); by += w1 * bf_hi(v1);
            ax += w2 * bf_lo(v2); ay += w2 * bf_hi(v2);
            bx += w3 * bf_lo(v3); by += w3 * bf_hi(v3);
            ax += w4 * bf_lo(v4); ay += w4 * bf_hi(v4);
            bx += w5 * bf_lo(v5); by += w5 * bf_hi(v5);
            ax += w6 * bf_lo(v6); ay += w6 * bf_hi(v6);
            bx += w7 * bf_lo(v7); by += w7 * bf_hi(v7);
        }
        ax += bx; ay += by;
        float zx = di * ax + bsx;
        float zy = di * ay + bsy;
        zx = zx > 0.f ? zx : pax * zx;
        zy = zy > 0.f ? zy : pay * zy;

        if (valid) {
            if (mode == 0) {
                uint32_t pk = (uint32_t)bf16rne(zx) | ((uint32_t)bf16rne(zy) << 16);
                z1b[(size_t)node * 64 + lane] = pk;
            } else {
                ((float2*)zoutf)[(size_t)node * 64 + lane] = make_float2(zx, zy);
            }
        }
        float cx = valid ? zx : 0.f, cy = valid ? zy : 0.f;
        if (uni) {
            psx += cx; psy += cy;
        } else if (valid) {                 // rare: block spans graphs
            int gr = batch[node];
            float* bp = &gout[(size_t)gr * 256 + col_off];
            atomicAdd(&bp[c], cx);
            atomicAdd(&bp[c + 1], cy);
        }
    }

    if (uni) {
        red[wv][c] = psx; red[wv][c + 1] = psy;
        __syncthreads();
        if (wv == 0) {
            float sx = red[0][c] + red[1][c] + red[2][c] + red[3][c];
            float sy = red[0][c + 1] + red[1][c + 1] + red[2][c + 1] + red[3][c + 1];
            float* bp = &gout[(size_t)g0 * 256 + col_off];
            atomicAdd(&bp[c], sx);
            atomicAdd(&bp[c + 1], sy);
        }
    }
}

extern "C" void kernel_launch(void* const* d_in, const int* in_sizes, int n_in,
                              void* d_out, int out_size, void* d_ws, size_t ws_size,
                              hipStream_t stream) {
    const float* x     = (const float*)d_in[0];
    const int*   eidx  = (const int*)d_in[1];
    const int*   batch = (const int*)d_in[2];
    const float* W1    = (const float*)d_in[3];
    const float* b1    = (const float*)d_in[4];
    const float* W2    = (const float*)d_in[5];
    const float* b2    = (const float*)d_in[6];
    const float* alpha = (const float*)d_in[7];

    const int N = in_sizes[2];
    const int E = in_sizes[1] / 2;
    const int G = (out_size - N * 128) / 256;

    const int* src = eidx;
    const int* dst = eidx + E;

    char* ws = (char*)d_ws;
    size_t off = 0;
    auto alloc = [&](size_t bytes) { void* q = ws + off; off = (off + bytes + 255) & ~(size_t)255; return q; };
    int*      cursor = (int*)alloc((size_t)(N + 1) * 4);
    uint16_t* col    = (uint16_t*)alloc((size_t)N * CAP * 2);
    uint32_t* zw     = (uint32_t*)alloc((size_t)(N + 1) * 128 * 2);  // +1 pad row (zeroed)
    uint32_t* z1b    = (uint32_t*)alloc((size_t)N * 128 * 2);
    uint16_t* Wf1    = (uint16_t*)alloc(128 * 128 * 2);
    uint16_t* Wf2    = (uint16_t*)alloc(128 * 128 * 2);

    float* z_out = (float*)d_out;
    float* g_out = (float*)d_out + (size_t)N * 128;

    int nbC      = (N + 512) / 512;            // cursor zero (N+1 entries)
    int nbZ      = (G * 256 / 4 + 511) / 512;  // g_out zero (float4)
    int fillGrid = (E + 1023) / 1024;          // 2 edges/thread x 512
    int gemmGrid = (N + 127) / 128;            // M=128 tiles x 512 thr
    int aggGrid  = (N + 15) / 16;              // 16 nodes/block
    int ndw      = N * 64;                     // zscale dwords
    int zsGrid   = (ndw + 511) / 512;

    k0<<<nbC + 8 + nbZ, 512, 0, stream>>>(cursor, nbC, N, W1, W2, Wf1, Wf2, g_out, nbZ, zw);
    k5<<<gemmGrid + fillGrid, 512, 0, stream>>>(x, Wf1, (uint16_t*)zw, N, gemmGrid,
                                                src, dst, cursor, col, E, fillGrid);
    zscale<<<zsGrid, 512, 0, stream>>>(zw, cursor, ndw);
    aggp<true><<<aggGrid, 256, 0, stream>>>(zw, cursor, col, b1, alpha, batch,
                                            g_out, 0, z1b, nullptr, 0, N);
    gemm2k<<<gemmGrid, 512, 0, stream>>>((const uint16_t*)z1b, Wf2, (uint16_t*)zw, N, cursor);
    aggp<true><<<aggGrid, 256, 0, stream>>>(zw, cursor, col, b2, alpha, batch,
                                            g_out, 128, nullptr, z_out, 1, N);
}